// Round 1
// baseline (595.014 us; speedup 1.0000x reference)
//
#include <hip/hip_runtime.h>

#define HIDDEN 64
#define N_GRAPHS 64

// ---------------------------------------------------------------------------
// Wave (64-lane) float sum reduction via butterfly shuffle.
static __device__ __forceinline__ float wave_reduce_sum(float v) {
    for (int off = 32; off; off >>= 1) v += __shfl_xor(v, off, 64);
    return v;
}

// ---------------------------------------------------------------------------
// 1) degree histogram of dst
__global__ void degree_kernel(const int* __restrict__ dst, int* __restrict__ deg, int E) {
    int e = blockIdx.x * blockDim.x + threadIdx.x;
    if (e < E) atomicAdd(&deg[dst[e]], 1);
}

// 2) exclusive scan of deg -> rowptr[0..N], single block of 1024 threads
__global__ void scan_kernel(const int* __restrict__ deg, int* __restrict__ rowptr, int N) {
    __shared__ int sums[1024];
    const int t = threadIdx.x;
    const int C = (N + 1023) / 1024;
    const int lo = t * C;
    const int hi = min(lo + C, N);
    int s = 0;
    for (int i = lo; i < hi; ++i) s += deg[i];
    sums[t] = s;
    __syncthreads();
    for (int off = 1; off < 1024; off <<= 1) {
        int v = (t >= off) ? sums[t - off] : 0;
        __syncthreads();
        sums[t] += v;
        __syncthreads();
    }
    int run = (t == 0) ? 0 : sums[t - 1];   // exclusive prefix
    for (int i = lo; i < hi; ++i) { rowptr[i] = run; run += deg[i]; }
    if (lo < N && hi == N) rowptr[N] = run;
}

// 3) scatter edges into CSR slots: csr_src[rowptr[d] + slot] = src(e)
__global__ void fill_kernel(const int* __restrict__ src, const int* __restrict__ dst,
                            const int* __restrict__ rowptr, int* __restrict__ cursor,
                            int* __restrict__ csr_src, int E) {
    int e = blockIdx.x * blockDim.x + threadIdx.x;
    if (e >= E) return;
    int d = dst[e];
    int slot = atomicAdd(&cursor[d], 1);
    csr_src[rowptr[d] + slot] = src[e];
}

// ---------------------------------------------------------------------------
// Layer 1: in_dim=3 -> 64.  One wave per node (grid-stride over nodes).
// lane = output channel. Neighbor agg of 3 floats via per-lane strided gather
// + butterfly reduce; weights held in registers (one column per lane).
__global__ __launch_bounds__(256) void layer1_kernel(
        const float* __restrict__ x, const int* __restrict__ rowptr,
        const int* __restrict__ csr_src,
        const float* __restrict__ W_rel, const float* __restrict__ W_root,
        const float* __restrict__ bias, float* __restrict__ h_out, int N) {
    const int lane = threadIdx.x & 63;
    const int wid = (blockIdx.x * blockDim.x + threadIdx.x) >> 6;
    const int nwaves = (gridDim.x * blockDim.x) >> 6;
    const float wr0 = W_rel[lane], wr1 = W_rel[64 + lane], wr2 = W_rel[128 + lane];
    const float wo0 = W_root[lane], wo1 = W_root[64 + lane], wo2 = W_root[128 + lane];
    const float bb = bias[lane];
    for (int node = wid; node < N; node += nwaves) {
        const int start = rowptr[node], end = rowptr[node + 1];
        float a0 = 0.f, a1 = 0.f, a2 = 0.f;
        for (int pos = start + lane; pos < end; pos += 64) {
            int j = csr_src[pos];
            a0 += x[j * 3 + 0];
            a1 += x[j * 3 + 1];
            a2 += x[j * 3 + 2];
        }
        a0 = wave_reduce_sum(a0);
        a1 = wave_reduce_sum(a1);
        a2 = wave_reduce_sum(a2);
        const float x0 = x[node * 3 + 0], x1 = x[node * 3 + 1], x2 = x[node * 3 + 2];
        float h = bb + a0 * wr0 + a1 * wr1 + a2 * wr2 + x0 * wo0 + x1 * wo1 + x2 * wo2;
        h_out[node * 64 + lane] = fmaxf(h, 0.f);
    }
}

// ---------------------------------------------------------------------------
// Layers 2/3: 64 -> 64. One wave per node, lane = channel.
// Neighbor rows are coalesced 256B reads. Matmul: acc/self values broadcast
// with v_readlane (fully unrolled), weights staged in LDS as float2 pairs.
template <bool RELU>
__global__ __launch_bounds__(256) void conv_kernel(
        const float* __restrict__ h_in, const int* __restrict__ rowptr,
        const int* __restrict__ csr_src,
        const float* __restrict__ W_rel, const float* __restrict__ W_root,
        const float* __restrict__ bias, float* __restrict__ h_out, int N) {
    __shared__ float2 sW[64 * 64];   // {W_rel[k][h], W_root[k][h]} interleaved, 32 KB
    const int tid = threadIdx.x;
    for (int i = tid; i < 64 * 64; i += 256) sW[i] = make_float2(W_rel[i], W_root[i]);
    __syncthreads();

    const int lane = tid & 63;
    const int wid = (blockIdx.x * 256 + tid) >> 6;
    const int nwaves = (gridDim.x * 256) >> 6;
    const float bb = bias[lane];

    for (int node = wid; node < N; node += nwaves) {
        const int start = rowptr[node];
        const int deg = rowptr[node + 1] - start;
        float acc0 = 0.f, acc1 = 0.f, acc2 = 0.f, acc3 = 0.f;
        for (int base = 0; base < deg; base += 64) {
            const int m = min(64, deg - base);
            int jreg = (lane < m) ? csr_src[start + base + lane] : 0;
            int k = 0;
            for (; k + 3 < m; k += 4) {
                int j0 = __shfl(jreg, k, 64);
                int j1 = __shfl(jreg, k + 1, 64);
                int j2 = __shfl(jreg, k + 2, 64);
                int j3 = __shfl(jreg, k + 3, 64);
                acc0 += h_in[j0 * 64 + lane];
                acc1 += h_in[j1 * 64 + lane];
                acc2 += h_in[j2 * 64 + lane];
                acc3 += h_in[j3 * 64 + lane];
            }
            for (; k < m; ++k) {
                int j = __shfl(jreg, k, 64);
                acc0 += h_in[j * 64 + lane];
            }
        }
        const float acc = (acc0 + acc1) + (acc2 + acc3);
        const float self = h_in[node * 64 + lane];

        float out = bb;
        #pragma unroll
        for (int k = 0; k < 64; ++k) {
            const float a = __shfl(acc, k, 64);   // v_readlane -> SGPR broadcast
            const float s = __shfl(self, k, 64);
            const float2 w = sW[k * 64 + lane];
            out += a * w.x + s * w.y;
        }
        if (RELU) out = fmaxf(out, 0.f);
        h_out[node * 64 + lane] = out;
    }
}

// ---------------------------------------------------------------------------
// Global mean pool: batch is sorted; each wave owns a contiguous chunk of
// nodes, accumulates in registers, flushes on graph-id change (few atomics).
__global__ __launch_bounds__(256) void pool_kernel(
        const float* __restrict__ h, const int* __restrict__ batch,
        float* __restrict__ pooled, int* __restrict__ counts, int N) {
    const int CHUNK = 256;
    const int lane = threadIdx.x & 63;
    const int wid = (blockIdx.x * blockDim.x + threadIdx.x) >> 6;
    const int lo = wid * CHUNK;
    if (lo >= N) return;
    const int hi = min(lo + CHUNK, N);
    int g_cur = batch[lo];
    float acc = 0.f;
    int cnt = 0;
    for (int n = lo; n < hi; ++n) {
        const int g = batch[n];
        if (g != g_cur) {
            atomicAdd(&pooled[g_cur * 64 + lane], acc);
            if (lane == 0) atomicAdd(&counts[g_cur], cnt);
            acc = 0.f; cnt = 0; g_cur = g;
        }
        acc += h[n * 64 + lane];
        cnt++;
    }
    atomicAdd(&pooled[g_cur * 64 + lane], acc);
    if (lane == 0) atomicAdd(&counts[g_cur], cnt);
}

// ---------------------------------------------------------------------------
// Heads: per graph, mean then two 64-dot products.
__global__ void head_kernel(const float* __restrict__ pooled, const int* __restrict__ counts,
                            const float* __restrict__ lin1_w, const float* __restrict__ lin1_b,
                            const float* __restrict__ lin2_w, const float* __restrict__ lin2_b,
                            float* __restrict__ out) {
    const int g = blockIdx.x;
    const int lane = threadIdx.x;
    const float c = fmaxf((float)counts[g], 1.0f);
    const float p = pooled[g * 64 + lane] / c;
    float d1 = wave_reduce_sum(p * lin1_w[lane]);
    float d2 = wave_reduce_sum(p * lin2_w[lane]);
    if (lane == 0) {
        out[g] = d1 + lin1_b[0];
        out[N_GRAPHS + g] = d2 + lin2_b[0];
    }
}

// ---------------------------------------------------------------------------
extern "C" void kernel_launch(void* const* d_in, const int* in_sizes, int n_in,
                              void* d_out, int out_size, void* d_ws, size_t ws_size,
                              hipStream_t stream) {
    const float* x       = (const float*)d_in[0];
    const int*   ei      = (const int*)d_in[1];
    const int*   batch   = (const int*)d_in[2];
    const float* W1_rel  = (const float*)d_in[3];
    const float* W1_root = (const float*)d_in[4];
    const float* b1      = (const float*)d_in[5];
    const float* W2_rel  = (const float*)d_in[6];
    const float* W2_root = (const float*)d_in[7];
    const float* b2      = (const float*)d_in[8];
    const float* W3_rel  = (const float*)d_in[9];
    const float* W3_root = (const float*)d_in[10];
    const float* b3      = (const float*)d_in[11];
    const float* lin1_w  = (const float*)d_in[12];
    const float* lin1_b  = (const float*)d_in[13];
    const float* lin2_w  = (const float*)d_in[14];
    const float* lin2_b  = (const float*)d_in[15];

    const int N = in_sizes[0] / 3;       // 50000
    const int E = in_sizes[1] / 2;       // 800000
    const int* src = ei;
    const int* dst = ei + E;

    // workspace layout (256B-aligned slabs)
    char* ws = (char*)d_ws;
    size_t off = 0;
    auto alloc = [&](size_t bytes) -> void* {
        void* p = ws + off;
        off += (bytes + 255) & ~(size_t)255;
        return p;
    };
    int*   deg     = (int*)alloc((size_t)N * 4);
    int*   rowptr  = (int*)alloc((size_t)(N + 1) * 4);
    int*   cursor  = (int*)alloc((size_t)N * 4);
    int*   csr_src = (int*)alloc((size_t)E * 4);
    float* hbuf0   = (float*)alloc((size_t)N * HIDDEN * 4);
    float* hbuf1   = (float*)alloc((size_t)N * HIDDEN * 4);
    float* pooled  = (float*)alloc((size_t)N_GRAPHS * HIDDEN * 4);
    int*   counts  = (int*)alloc((size_t)N_GRAPHS * 4);

    // zero what needs zeroing (ws is poisoned 0xAA before every launch)
    hipMemsetAsync(deg, 0, (size_t)N * 4, stream);
    hipMemsetAsync(cursor, 0, (size_t)N * 4, stream);
    hipMemsetAsync(pooled, 0, (size_t)N_GRAPHS * HIDDEN * 4 + 256, stream); // pooled + counts slab start
    hipMemsetAsync(counts, 0, (size_t)N_GRAPHS * 4, stream);

    const int eb = (E + 255) / 256;
    degree_kernel<<<eb, 256, 0, stream>>>(dst, deg, E);
    scan_kernel<<<1, 1024, 0, stream>>>(deg, rowptr, N);
    fill_kernel<<<eb, 256, 0, stream>>>(src, dst, rowptr, cursor, csr_src, E);

    layer1_kernel<<<1024, 256, 0, stream>>>(x, rowptr, csr_src, W1_rel, W1_root, b1, hbuf0, N);
    conv_kernel<true ><<<1024, 256, 0, stream>>>(hbuf0, rowptr, csr_src, W2_rel, W2_root, b2, hbuf1, N);
    conv_kernel<false><<<1024, 256, 0, stream>>>(hbuf1, rowptr, csr_src, W3_rel, W3_root, b3, hbuf0, N);

    const int pool_waves = (N + 255) / 256;
    const int pool_blocks = (pool_waves + 3) / 4;
    pool_kernel<<<pool_blocks, 256, 0, stream>>>(hbuf0, batch, pooled, counts, N);
    head_kernel<<<N_GRAPHS, 64, 0, stream>>>(pooled, counts, lin1_w, lin1_b, lin2_w, lin2_b,
                                             (float*)d_out);
}

// Round 2
// 514.773 us; speedup vs baseline: 1.1559x; 1.1559x over previous
//
#include <hip/hip_runtime.h>

#define HIDDEN 64
#define N_GRAPHS 64

typedef unsigned int u32;
typedef unsigned short u16;

// ---------------------------------------------------------------------------
// bf16 helpers (stored as u16, packed pairs in u32)
static __device__ __forceinline__ float bf_lo(u32 u) { return __uint_as_float(u << 16); }
static __device__ __forceinline__ float bf_hi(u32 u) { return __uint_as_float(u & 0xFFFF0000u); }
static __device__ __forceinline__ float bf2f(u16 v) { return __uint_as_float(((u32)v) << 16); }
static __device__ __forceinline__ u16 f2bf(float f) {          // round-to-nearest-even
    u32 x = __float_as_uint(f);
    return (u16)((x + 0x7FFFu + ((x >> 16) & 1u)) >> 16);
}
static __device__ __forceinline__ u32 pack2(float a, float b) {
    return (u32)f2bf(a) | ((u32)f2bf(b) << 16);
}

static __device__ __forceinline__ float wave_reduce_sum(float v) {
    for (int off = 32; off; off >>= 1) v += __shfl_xor(v, off, 64);
    return v;
}

// ---------------------------------------------------------------------------
// CSR build: degree histogram, 3-phase scan, slot fill
__global__ void degree_kernel(const int* __restrict__ dst, int* __restrict__ deg, int E) {
    int e = blockIdx.x * blockDim.x + threadIdx.x;
    if (e < E) atomicAdd(&deg[dst[e]], 1);
}

__global__ void scan_p1(const int* __restrict__ deg, int* __restrict__ partial, int N) {
    __shared__ int s[256];
    const int t = threadIdx.x, i = blockIdx.x * 256 + t;
    s[t] = (i < N) ? deg[i] : 0;
    __syncthreads();
    for (int off = 128; off; off >>= 1) {
        if (t < off) s[t] += s[t + off];
        __syncthreads();
    }
    if (t == 0) partial[blockIdx.x] = s[0];
}

__global__ void scan_p2(const int* __restrict__ partial, int* __restrict__ boff,
                        int nb, int* __restrict__ rowptr, int N, int E) {
    __shared__ int s[256];
    const int t = threadIdx.x;
    int carry = 0;
    for (int base = 0; base < nb; base += 256) {
        int v = (base + t < nb) ? partial[base + t] : 0;
        s[t] = v;
        __syncthreads();
        for (int off = 1; off < 256; off <<= 1) {
            int u = (t >= off) ? s[t - off] : 0;
            __syncthreads();
            s[t] += u;
            __syncthreads();
        }
        if (base + t < nb) boff[base + t] = carry + s[t] - v;
        int tot = s[255];
        __syncthreads();
        carry += tot;
    }
    if (t == 0) rowptr[N] = E;
}

__global__ void scan_p3(const int* __restrict__ deg, const int* __restrict__ boff,
                        int* __restrict__ rowptr, int N) {
    __shared__ int s[256];
    const int t = threadIdx.x, i = blockIdx.x * 256 + t;
    int v = (i < N) ? deg[i] : 0;
    s[t] = v;
    __syncthreads();
    for (int off = 1; off < 256; off <<= 1) {
        int u = (t >= off) ? s[t - off] : 0;
        __syncthreads();
        s[t] += u;
        __syncthreads();
    }
    if (i < N) rowptr[i] = boff[blockIdx.x] + s[t] - v;
}

__global__ void fill_kernel(const int* __restrict__ src, const int* __restrict__ dst,
                            const int* __restrict__ rowptr, int* __restrict__ cursor,
                            int* __restrict__ csr_src, int E) {
    int e = blockIdx.x * blockDim.x + threadIdx.x;
    if (e >= E) return;
    int d = dst[e];
    int slot = atomicAdd(&cursor[d], 1);
    csr_src[rowptr[d] + slot] = src[e];
}

// ---------------------------------------------------------------------------
// dense1: P = x@W1_rel, R = x@W1_root + b1   (IN_DIM=3, outputs bf16)
// one wave per 4 nodes; lane = channel; x values broadcast-loaded.
__global__ __launch_bounds__(256) void dense1_kernel(
        const float* __restrict__ x, const float* __restrict__ Wrel,
        const float* __restrict__ Wroot, const float* __restrict__ bias,
        u16* __restrict__ P, u16* __restrict__ R, int N) {
    const int lane = threadIdx.x & 63;
    const int gw = (blockIdx.x * 256 + threadIdx.x) >> 6;
    const int n0 = gw * 4;
    if (n0 >= N) return;
    const float wr0 = Wrel[lane], wr1 = Wrel[64 + lane], wr2 = Wrel[128 + lane];
    const float wo0 = Wroot[lane], wo1 = Wroot[64 + lane], wo2 = Wroot[128 + lane];
    const float bb = bias[lane];
    const int n1 = min(n0 + 4, N);
    for (int n = n0; n < n1; ++n) {
        const float x0 = x[n * 3 + 0], x1 = x[n * 3 + 1], x2 = x[n * 3 + 2];
        const float p = x0 * wr0 + x1 * wr1 + x2 * wr2;
        const float r = x0 * wo0 + x1 * wo1 + x2 * wo2 + bb;
        P[(size_t)n * 64 + lane] = f2bf(p);
        R[(size_t)n * 64 + lane] = f2bf(r);
    }
}

// ---------------------------------------------------------------------------
// dense (64->64 twice): P = h@Wrel, R = h@Wroot + b.  h is bf16, weights f32
// staged in LDS interleaved; each wave handles 4 nodes to amortize LDS reads.
__global__ __launch_bounds__(256) void dense_kernel(
        const u16* __restrict__ h_in, const float* __restrict__ Wrel,
        const float* __restrict__ Wroot, const float* __restrict__ bias,
        u16* __restrict__ P, u16* __restrict__ R, int N) {
    __shared__ float2 sW[64 * 64];   // 32 KB: {Wrel[k][h], Wroot[k][h]}
    const int tid = threadIdx.x;
    for (int i = tid; i < 64 * 64; i += 256) sW[i] = make_float2(Wrel[i], Wroot[i]);
    __syncthreads();

    const int lane = tid & 63;
    const int gw = (blockIdx.x * 256 + tid) >> 6;
    const int n0 = gw * 4;
    if (n0 >= N) return;

    float s0 = (n0 + 0 < N) ? bf2f(h_in[(size_t)(n0 + 0) * 64 + lane]) : 0.f;
    float s1 = (n0 + 1 < N) ? bf2f(h_in[(size_t)(n0 + 1) * 64 + lane]) : 0.f;
    float s2 = (n0 + 2 < N) ? bf2f(h_in[(size_t)(n0 + 2) * 64 + lane]) : 0.f;
    float s3 = (n0 + 3 < N) ? bf2f(h_in[(size_t)(n0 + 3) * 64 + lane]) : 0.f;

    float p0 = 0.f, p1 = 0.f, p2 = 0.f, p3 = 0.f;
    float r0 = 0.f, r1 = 0.f, r2 = 0.f, r3 = 0.f;
    #pragma unroll
    for (int k = 0; k < 64; ++k) {
        const float2 w = sW[k * 64 + lane];
        const float a0 = __shfl(s0, k, 64);
        const float a1 = __shfl(s1, k, 64);
        const float a2 = __shfl(s2, k, 64);
        const float a3 = __shfl(s3, k, 64);
        p0 += a0 * w.x; r0 += a0 * w.y;
        p1 += a1 * w.x; r1 += a1 * w.y;
        p2 += a2 * w.x; r2 += a2 * w.y;
        p3 += a3 * w.x; r3 += a3 * w.y;
    }
    const float bb = bias[lane];
    if (n0 + 0 < N) { P[(size_t)(n0+0)*64+lane] = f2bf(p0); R[(size_t)(n0+0)*64+lane] = f2bf(r0 + bb); }
    if (n0 + 1 < N) { P[(size_t)(n0+1)*64+lane] = f2bf(p1); R[(size_t)(n0+1)*64+lane] = f2bf(r1 + bb); }
    if (n0 + 2 < N) { P[(size_t)(n0+2)*64+lane] = f2bf(p2); R[(size_t)(n0+2)*64+lane] = f2bf(r2 + bb); }
    if (n0 + 3 < N) { P[(size_t)(n0+3)*64+lane] = f2bf(p3); R[(size_t)(n0+3)*64+lane] = f2bf(r3 + bb); }
}

// ---------------------------------------------------------------------------
// gather: h_out[i] = act( sum_{j->i} P[j] + R[i] ), all rows 64 x bf16.
// One wave per node. 8 lane-groups x 16B -> 8 neighbor rows per load instr,
// unrolled x2 (16 rows in flight). No LDS, low VGPR -> high occupancy.
// Writes h in-place over R (R[i] is only ever touched by node i's own wave).
template <bool RELU>
__global__ __launch_bounds__(256) void gather_kernel(
        const u16* __restrict__ P, u16* __restrict__ R_h,
        const int* __restrict__ rowptr, const int* __restrict__ csr_src, int N) {
    const int lane = threadIdx.x & 63;
    const int grp = lane >> 3;       // neighbor slot within round
    const int c = lane & 7;          // 16B chunk within row (8 bf16 channels)
    const int node = (blockIdx.x * 256 + threadIdx.x) >> 6;
    if (node >= N) return;
    const int start = rowptr[node];
    const int deg = rowptr[node + 1] - start;

    float acc[8] = {0.f, 0.f, 0.f, 0.f, 0.f, 0.f, 0.f, 0.f};

    for (int base = 0; base < deg; base += 64) {
        const int m = min(64, deg - base);
        int jreg = (lane < m) ? csr_src[start + base + lane] : 0;
        int r = 0;
        for (; r + 16 <= m; r += 16) {
            const int j0 = __shfl(jreg, r + grp, 64);
            const int j1 = __shfl(jreg, r + 8 + grp, 64);
            const uint4 v0 = *((const uint4*)(P + (size_t)j0 * 64) + c);
            const uint4 v1 = *((const uint4*)(P + (size_t)j1 * 64) + c);
            acc[0] += bf_lo(v0.x); acc[1] += bf_hi(v0.x);
            acc[2] += bf_lo(v0.y); acc[3] += bf_hi(v0.y);
            acc[4] += bf_lo(v0.z); acc[5] += bf_hi(v0.z);
            acc[6] += bf_lo(v0.w); acc[7] += bf_hi(v0.w);
            acc[0] += bf_lo(v1.x); acc[1] += bf_hi(v1.x);
            acc[2] += bf_lo(v1.y); acc[3] += bf_hi(v1.y);
            acc[4] += bf_lo(v1.z); acc[5] += bf_hi(v1.z);
            acc[6] += bf_lo(v1.w); acc[7] += bf_hi(v1.w);
        }
        for (; r < m; r += 8) {
            const int srcl = r + grp;
            const int j = __shfl(jreg, srcl, 64);
            if (srcl < m) {
                const uint4 v = *((const uint4*)(P + (size_t)j * 64) + c);
                acc[0] += bf_lo(v.x); acc[1] += bf_hi(v.x);
                acc[2] += bf_lo(v.y); acc[3] += bf_hi(v.y);
                acc[4] += bf_lo(v.z); acc[5] += bf_hi(v.z);
                acc[6] += bf_lo(v.w); acc[7] += bf_hi(v.w);
            }
        }
    }
    // reduce the 8 lane-groups (each lane ends with totals for channels 8c..8c+7)
    #pragma unroll
    for (int off = 8; off <= 32; off <<= 1) {
        #pragma unroll
        for (int i = 0; i < 8; ++i) acc[i] += __shfl_xor(acc[i], off, 64);
    }
    if (lane < 8) {
        const uint4 rv = *((const uint4*)(R_h + (size_t)node * 64) + lane);
        float o[8];
        o[0] = acc[0] + bf_lo(rv.x); o[1] = acc[1] + bf_hi(rv.x);
        o[2] = acc[2] + bf_lo(rv.y); o[3] = acc[3] + bf_hi(rv.y);
        o[4] = acc[4] + bf_lo(rv.z); o[5] = acc[5] + bf_hi(rv.z);
        o[6] = acc[6] + bf_lo(rv.w); o[7] = acc[7] + bf_hi(rv.w);
        if (RELU) {
            #pragma unroll
            for (int i = 0; i < 8; ++i) o[i] = fmaxf(o[i], 0.f);
        }
        uint4 sv;
        sv.x = pack2(o[0], o[1]); sv.y = pack2(o[2], o[3]);
        sv.z = pack2(o[4], o[5]); sv.w = pack2(o[6], o[7]);
        *((uint4*)(R_h + (size_t)node * 64) + lane) = sv;
    }
}

// ---------------------------------------------------------------------------
// Global mean pool over sorted batch ids; register accumulation, flush on
// graph transitions (few hundred atomics total). h is bf16.
__global__ __launch_bounds__(256) void pool_kernel(
        const u16* __restrict__ h, const int* __restrict__ batch,
        float* __restrict__ pooled, int* __restrict__ counts, int N) {
    const int CHUNK = 256;
    const int lane = threadIdx.x & 63;
    const int wid = (blockIdx.x * blockDim.x + threadIdx.x) >> 6;
    const int lo = wid * CHUNK;
    if (lo >= N) return;
    const int hi = min(lo + CHUNK, N);
    int g_cur = batch[lo];
    float acc = 0.f;
    int cnt = 0;
    for (int n = lo; n < hi; ++n) {
        const int g = batch[n];
        if (g != g_cur) {
            atomicAdd(&pooled[g_cur * 64 + lane], acc);
            if (lane == 0) atomicAdd(&counts[g_cur], cnt);
            acc = 0.f; cnt = 0; g_cur = g;
        }
        acc += bf2f(h[(size_t)n * 64 + lane]);
        cnt++;
    }
    atomicAdd(&pooled[g_cur * 64 + lane], acc);
    if (lane == 0) atomicAdd(&counts[g_cur], cnt);
}

__global__ void head_kernel(const float* __restrict__ pooled, const int* __restrict__ counts,
                            const float* __restrict__ lin1_w, const float* __restrict__ lin1_b,
                            const float* __restrict__ lin2_w, const float* __restrict__ lin2_b,
                            float* __restrict__ out) {
    const int g = blockIdx.x;
    const int lane = threadIdx.x;
    const float c = fmaxf((float)counts[g], 1.0f);
    const float p = pooled[g * 64 + lane] / c;
    float d1 = wave_reduce_sum(p * lin1_w[lane]);
    float d2 = wave_reduce_sum(p * lin2_w[lane]);
    if (lane == 0) {
        out[g] = d1 + lin1_b[0];
        out[N_GRAPHS + g] = d2 + lin2_b[0];
    }
}

// ---------------------------------------------------------------------------
extern "C" void kernel_launch(void* const* d_in, const int* in_sizes, int n_in,
                              void* d_out, int out_size, void* d_ws, size_t ws_size,
                              hipStream_t stream) {
    const float* x       = (const float*)d_in[0];
    const int*   ei      = (const int*)d_in[1];
    const int*   batch   = (const int*)d_in[2];
    const float* W1_rel  = (const float*)d_in[3];
    const float* W1_root = (const float*)d_in[4];
    const float* b1      = (const float*)d_in[5];
    const float* W2_rel  = (const float*)d_in[6];
    const float* W2_root = (const float*)d_in[7];
    const float* b2      = (const float*)d_in[8];
    const float* W3_rel  = (const float*)d_in[9];
    const float* W3_root = (const float*)d_in[10];
    const float* b3      = (const float*)d_in[11];
    const float* lin1_w  = (const float*)d_in[12];
    const float* lin1_b  = (const float*)d_in[13];
    const float* lin2_w  = (const float*)d_in[14];
    const float* lin2_b  = (const float*)d_in[15];

    const int N = in_sizes[0] / 3;       // 50000
    const int E = in_sizes[1] / 2;       // 800000
    const int* src = ei;
    const int* dst = ei + E;

    char* ws = (char*)d_ws;
    size_t off = 0;
    auto alloc = [&](size_t bytes) -> void* {
        void* p = ws + off;
        off += (bytes + 255) & ~(size_t)255;
        return p;
    };
    int* deg     = (int*)alloc((size_t)N * 4);
    int* rowptr  = (int*)alloc((size_t)(N + 1) * 4);
    int* cursor  = (int*)alloc((size_t)N * 4);
    int* csr_src = (int*)alloc((size_t)E * 4);
    int* partial = (int*)alloc(1024);
    int* boff    = (int*)alloc(1024);
    u16* bufA    = (u16*)alloc((size_t)N * HIDDEN * 2);
    u16* bufP    = (u16*)alloc((size_t)N * HIDDEN * 2);
    u16* bufB    = (u16*)alloc((size_t)N * HIDDEN * 2);
    float* pooled = (float*)alloc((size_t)N_GRAPHS * HIDDEN * 4);
    int* counts   = (int*)alloc((size_t)N_GRAPHS * 4);

    hipMemsetAsync(deg, 0, (size_t)N * 4, stream);
    hipMemsetAsync(cursor, 0, (size_t)N * 4, stream);
    hipMemsetAsync(pooled, 0, (size_t)N_GRAPHS * HIDDEN * 4, stream);
    hipMemsetAsync(counts, 0, (size_t)N_GRAPHS * 4, stream);

    const int eb = (E + 255) / 256;
    const int nb = (N + 255) / 256;                 // 196 scan blocks
    degree_kernel<<<eb, 256, 0, stream>>>(dst, deg, E);
    scan_p1<<<nb, 256, 0, stream>>>(deg, partial, N);
    scan_p2<<<1, 256, 0, stream>>>(partial, boff, nb, rowptr, N, E);
    scan_p3<<<nb, 256, 0, stream>>>(deg, boff, rowptr, N);
    fill_kernel<<<eb, 256, 0, stream>>>(src, dst, rowptr, cursor, csr_src, E);

    const int gb = (N + 3) / 4;                     // gather: 1 wave/node, 4/block
    const int db = (N + 15) / 16;                   // dense: 4 nodes/wave, 16/block

    dense1_kernel<<<db, 256, 0, stream>>>(x, W1_rel, W1_root, b1, bufP, bufB, N);
    gather_kernel<true ><<<gb, 256, 0, stream>>>(bufP, bufB, rowptr, csr_src, N);  // h1 in bufB
    dense_kernel<<<db, 256, 0, stream>>>(bufB, W2_rel, W2_root, b2, bufP, bufA, N);
    gather_kernel<true ><<<gb, 256, 0, stream>>>(bufP, bufA, rowptr, csr_src, N);  // h2 in bufA
    dense_kernel<<<db, 256, 0, stream>>>(bufA, W3_rel, W3_root, b3, bufP, bufB, N);
    gather_kernel<false><<<gb, 256, 0, stream>>>(bufP, bufB, rowptr, csr_src, N);  // h3 in bufB

    const int pool_waves = (N + 255) / 256;
    const int pool_blocks = (pool_waves + 3) / 4;
    pool_kernel<<<pool_blocks, 256, 0, stream>>>(bufB, batch, pooled, counts, N);
    head_kernel<<<N_GRAPHS, 64, 0, stream>>>(pooled, counts, lin1_w, lin1_b, lin2_w, lin2_b,
                                             (float*)d_out);
}

// Round 3
// 353.684 us; speedup vs baseline: 1.6823x; 1.4555x over previous
//
#include <hip/hip_runtime.h>

#define HIDDEN 64
#define N_GRAPHS 64

typedef unsigned int u32;
typedef unsigned short u16;

typedef __attribute__((ext_vector_type(8))) short short8;
typedef __attribute__((ext_vector_type(4))) float f32x4;

union U4S8 { uint4 u; short8 s; };
union U16x8 { u16 v[8]; uint4 u; };

// ---------------------------------------------------------------------------
// bf16 helpers
static __device__ __forceinline__ float bf_lo(u32 u) { return __uint_as_float(u << 16); }
static __device__ __forceinline__ float bf_hi(u32 u) { return __uint_as_float(u & 0xFFFF0000u); }
static __device__ __forceinline__ float bf2f(u16 v) { return __uint_as_float(((u32)v) << 16); }
static __device__ __forceinline__ u16 f2bf(float f) {          // round-to-nearest-even
    u32 x = __float_as_uint(f);
    return (u16)((x + 0x7FFFu + ((x >> 16) & 1u)) >> 16);
}
static __device__ __forceinline__ u32 pack2(float a, float b) {
    return (u32)f2bf(a) | ((u32)f2bf(b) << 16);
}

static __device__ __forceinline__ float wave_reduce_sum(float v) {
    for (int off = 32; off; off >>= 1) v += __shfl_xor(v, off, 64);
    return v;
}

// ---------------------------------------------------------------------------
// CSR build
__global__ void degree_kernel(const int* __restrict__ dst, int* __restrict__ deg, int E) {
    int e = blockIdx.x * blockDim.x + threadIdx.x;
    if (e < E) atomicAdd(&deg[dst[e]], 1);
}

__global__ void scan_p1(const int* __restrict__ deg, int* __restrict__ partial, int N) {
    __shared__ int s[256];
    const int t = threadIdx.x, i = blockIdx.x * 256 + t;
    s[t] = (i < N) ? deg[i] : 0;
    __syncthreads();
    for (int off = 128; off; off >>= 1) {
        if (t < off) s[t] += s[t + off];
        __syncthreads();
    }
    if (t == 0) partial[blockIdx.x] = s[0];
}

__global__ void scan_p2(const int* __restrict__ partial, int* __restrict__ boff,
                        int nb, int* __restrict__ rowptr, int N, int E) {
    __shared__ int s[256];
    const int t = threadIdx.x;
    int carry = 0;
    for (int base = 0; base < nb; base += 256) {
        int v = (base + t < nb) ? partial[base + t] : 0;
        s[t] = v;
        __syncthreads();
        for (int off = 1; off < 256; off <<= 1) {
            int u = (t >= off) ? s[t - off] : 0;
            __syncthreads();
            s[t] += u;
            __syncthreads();
        }
        if (base + t < nb) boff[base + t] = carry + s[t] - v;
        int tot = s[255];
        __syncthreads();
        carry += tot;
    }
    if (t == 0) rowptr[N] = E;
}

// also seeds cursor = rowptr so fill needs no separate rowptr load/memset
__global__ void scan_p3(const int* __restrict__ deg, const int* __restrict__ boff,
                        int* __restrict__ rowptr, int* __restrict__ cursor, int N) {
    __shared__ int s[256];
    const int t = threadIdx.x, i = blockIdx.x * 256 + t;
    int v = (i < N) ? deg[i] : 0;
    s[t] = v;
    __syncthreads();
    for (int off = 1; off < 256; off <<= 1) {
        int u = (t >= off) ? s[t - off] : 0;
        __syncthreads();
        s[t] += u;
        __syncthreads();
    }
    if (i < N) {
        int rp = boff[blockIdx.x] + s[t] - v;
        rowptr[i] = rp;
        cursor[i] = rp;
    }
}

__global__ void fill_kernel(const int* __restrict__ src, const int* __restrict__ dst,
                            int* __restrict__ cursor, int* __restrict__ csr_src, int E) {
    int e = blockIdx.x * blockDim.x + threadIdx.x;
    if (e >= E) return;
    int slot = atomicAdd(&cursor[dst[e]], 1);   // cursor pre-seeded with rowptr
    csr_src[slot] = src[e];
}

// ---------------------------------------------------------------------------
// dense1: P = x@W1_rel, R = x@W1_root + b1   (IN_DIM=3, outputs bf16)
__global__ __launch_bounds__(256) void dense1_kernel(
        const float* __restrict__ x, const float* __restrict__ Wrel,
        const float* __restrict__ Wroot, const float* __restrict__ bias,
        u16* __restrict__ P, u16* __restrict__ R, int N) {
    const int lane = threadIdx.x & 63;
    const int gw = (blockIdx.x * 256 + threadIdx.x) >> 6;
    const int n0 = gw * 4;
    if (n0 >= N) return;
    const float wr0 = Wrel[lane], wr1 = Wrel[64 + lane], wr2 = Wrel[128 + lane];
    const float wo0 = Wroot[lane], wo1 = Wroot[64 + lane], wo2 = Wroot[128 + lane];
    const float bb = bias[lane];
    const int n1 = min(n0 + 4, N);
    for (int n = n0; n < n1; ++n) {
        const float x0 = x[n * 3 + 0], x1 = x[n * 3 + 1], x2 = x[n * 3 + 2];
        const float p = x0 * wr0 + x1 * wr1 + x2 * wr2;
        const float r = x0 * wo0 + x1 * wo1 + x2 * wo2 + bb;
        P[(size_t)n * 64 + lane] = f2bf(p);
        R[(size_t)n * 64 + lane] = f2bf(r);
    }
}

// ---------------------------------------------------------------------------
// Prepack W = [Wrel | Wroot] (64K x 128N) into MFMA B-fragment lane order:
// frag f = t*2+kc (t = 16-col tile, kc = 32-k chunk); lane l; element j:
//   B[k = kc*32 + (l>>4)*8 + j][n = t*16 + (l&15)]
__global__ void prepack_kernel(const float* __restrict__ Wrel,
                               const float* __restrict__ Wroot,
                               u16* __restrict__ Bpk) {
    const int tid = threadIdx.x;            // 1024 threads
    const int f = tid >> 6, l = tid & 63;
    const int t = f >> 1, kc = f & 1;
    const int kb = kc * 32 + (l >> 4) * 8;
    const int n = t * 16 + (l & 15);
    U16x8 o;
    #pragma unroll
    for (int j = 0; j < 8; ++j) {
        const int k = kb + j;
        const float w = (n < 64) ? Wrel[k * 64 + n] : Wroot[k * 64 + (n - 64)];
        o.v[j] = f2bf(w);
    }
    ((uint4*)Bpk)[tid] = o.u;
}

// ---------------------------------------------------------------------------
// dense (64->64): [16 nodes x 64] @ [64 x 128] per wave via 16 MFMAs.
// B-frags live in registers (64 VGPRs), loaded from the prepacked buffer.
__global__ __launch_bounds__(256) void dense_mfma_kernel(
        const u16* __restrict__ h_in, const u16* __restrict__ Bpk,
        const float* __restrict__ bias, u16* __restrict__ P, u16* __restrict__ R,
        int Ngrp) {
    const int lane = threadIdx.x & 63;
    const int wid = (blockIdx.x * 256 + threadIdx.x) >> 6;
    if (wid >= Ngrp) return;

    U4S8 bf[16];
    const uint4* bp = (const uint4*)Bpk;
    #pragma unroll
    for (int f = 0; f < 16; ++f) bf[f].u = bp[f * 64 + lane];

    const int n0 = wid * 16;
    const int row = lane & 15, quad = lane >> 4;
    const u16* arow = h_in + (size_t)(n0 + row) * 64 + quad * 8;
    U4S8 a0, a1;
    a0.u = *(const uint4*)(arow);
    a1.u = *(const uint4*)(arow + 32);

    f32x4 acc[8];
    #pragma unroll
    for (int t = 0; t < 8; ++t) {
        f32x4 z = {0.f, 0.f, 0.f, 0.f};
        z = __builtin_amdgcn_mfma_f32_16x16x32_bf16(a0.s, bf[t * 2 + 0].s, z, 0, 0, 0);
        acc[t] = __builtin_amdgcn_mfma_f32_16x16x32_bf16(a1.s, bf[t * 2 + 1].s, z, 0, 0, 0);
    }

    const int col = lane & 15;
    #pragma unroll
    for (int t = 0; t < 4; ++t) {
        #pragma unroll
        for (int r = 0; r < 4; ++r) {
            const int node = n0 + quad * 4 + r;
            P[(size_t)node * 64 + t * 16 + col] = f2bf(acc[t][r]);
        }
    }
    #pragma unroll
    for (int t = 0; t < 4; ++t) {
        const float bb = bias[t * 16 + col];
        #pragma unroll
        for (int r = 0; r < 4; ++r) {
            const int node = n0 + quad * 4 + r;
            R[(size_t)node * 64 + t * 16 + col] = f2bf(acc[4 + t][r] + bb);
        }
    }
}

// ---------------------------------------------------------------------------
// gather: h_out[i] = act( sum_{j->i} P[j] + R[i] ).  2 nodes per wave
// (32 lanes each: 4 lane-groups x 8 chunks), two independent memory chains
// per wave for 2x MLP.  Wave-uniform loop bounds so shuffles stay defined.
template <bool RELU>
__global__ __launch_bounds__(256) void gather_kernel(
        const u16* __restrict__ P, u16* __restrict__ R_h,
        const int* __restrict__ rowptr, const int* __restrict__ csr_src, int N) {
    const int lane = threadIdx.x & 63;
    const int half = lane >> 5;        // which node of the pair
    const int hl = lane & 31;
    const int grp = hl >> 3;           // neighbor slot within a 4-row round
    const int c = hl & 7;              // 16B chunk (8 bf16 channels)
    const int wid = (blockIdx.x * 256 + threadIdx.x) >> 6;
    const int node = wid * 2 + half;

    int start = 0, deg = 0;
    if (node < N) { start = rowptr[node]; deg = rowptr[node + 1] - start; }
    const int degw = max(deg, __shfl_xor(deg, 32, 64));   // wave-uniform bound

    float acc[8] = {0.f, 0.f, 0.f, 0.f, 0.f, 0.f, 0.f, 0.f};

    for (int base = 0; base < degw; base += 32) {
        const int m = min(32, max(deg - base, 0));        // this half's rows
        const int mo = __shfl_xor(m, 32, 64);
        const int mmin = min(m, mo), mmax = max(m, mo);   // wave-uniform
        int jreg = (hl < m) ? csr_src[start + base + hl] : 0;
        int r = 0;
        for (; r + 8 <= mmin; r += 8) {                   // both halves full
            const int j0 = __shfl(jreg, half * 32 + r + grp, 64);
            const int j1 = __shfl(jreg, half * 32 + r + 4 + grp, 64);
            const uint4 v0 = *((const uint4*)(P + (size_t)j0 * 64) + c);
            const uint4 v1 = *((const uint4*)(P + (size_t)j1 * 64) + c);
            acc[0] += bf_lo(v0.x); acc[1] += bf_hi(v0.x);
            acc[2] += bf_lo(v0.y); acc[3] += bf_hi(v0.y);
            acc[4] += bf_lo(v0.z); acc[5] += bf_hi(v0.z);
            acc[6] += bf_lo(v0.w); acc[7] += bf_hi(v0.w);
            acc[0] += bf_lo(v1.x); acc[1] += bf_hi(v1.x);
            acc[2] += bf_lo(v1.y); acc[3] += bf_hi(v1.y);
            acc[4] += bf_lo(v1.z); acc[5] += bf_hi(v1.z);
            acc[6] += bf_lo(v1.w); acc[7] += bf_hi(v1.w);
        }
        for (; r < mmax; r += 4) {                        // masked tail
            const int sl = r + grp;
            const int j = __shfl(jreg, half * 32 + (sl & 31), 64);
            if (sl < m) {
                const uint4 v = *((const uint4*)(P + (size_t)j * 64) + c);
                acc[0] += bf_lo(v.x); acc[1] += bf_hi(v.x);
                acc[2] += bf_lo(v.y); acc[3] += bf_hi(v.y);
                acc[4] += bf_lo(v.z); acc[5] += bf_hi(v.z);
                acc[6] += bf_lo(v.w); acc[7] += bf_hi(v.w);
            }
        }
    }
    // reduce the 4 lane-groups within each 32-lane half
    #pragma unroll
    for (int i = 0; i < 8; ++i) {
        acc[i] += __shfl_xor(acc[i], 8, 64);
        acc[i] += __shfl_xor(acc[i], 16, 64);
    }
    if (hl < 8 && node < N) {          // lane c==hl holds chunk hl totals
        const uint4 rv = *((const uint4*)(R_h + (size_t)node * 64) + hl);
        float o[8];
        o[0] = acc[0] + bf_lo(rv.x); o[1] = acc[1] + bf_hi(rv.x);
        o[2] = acc[2] + bf_lo(rv.y); o[3] = acc[3] + bf_hi(rv.y);
        o[4] = acc[4] + bf_lo(rv.z); o[5] = acc[5] + bf_hi(rv.z);
        o[6] = acc[6] + bf_lo(rv.w); o[7] = acc[7] + bf_hi(rv.w);
        if (RELU) {
            #pragma unroll
            for (int i = 0; i < 8; ++i) o[i] = fmaxf(o[i], 0.f);
        }
        uint4 sv;
        sv.x = pack2(o[0], o[1]); sv.y = pack2(o[2], o[3]);
        sv.z = pack2(o[4], o[5]); sv.w = pack2(o[6], o[7]);
        *((uint4*)(R_h + (size_t)node * 64) + hl) = sv;
    }
}

// ---------------------------------------------------------------------------
__global__ __launch_bounds__(256) void pool_kernel(
        const u16* __restrict__ h, const int* __restrict__ batch,
        float* __restrict__ pooled, int* __restrict__ counts, int N) {
    const int CHUNK = 256;
    const int lane = threadIdx.x & 63;
    const int wid = (blockIdx.x * blockDim.x + threadIdx.x) >> 6;
    const int lo = wid * CHUNK;
    if (lo >= N) return;
    const int hi = min(lo + CHUNK, N);
    int g_cur = batch[lo];
    float acc = 0.f;
    int cnt = 0;
    for (int n = lo; n < hi; ++n) {
        const int g = batch[n];
        if (g != g_cur) {
            atomicAdd(&pooled[g_cur * 64 + lane], acc);
            if (lane == 0) atomicAdd(&counts[g_cur], cnt);
            acc = 0.f; cnt = 0; g_cur = g;
        }
        acc += bf2f(h[(size_t)n * 64 + lane]);
        cnt++;
    }
    atomicAdd(&pooled[g_cur * 64 + lane], acc);
    if (lane == 0) atomicAdd(&counts[g_cur], cnt);
}

__global__ void head_kernel(const float* __restrict__ pooled, const int* __restrict__ counts,
                            const float* __restrict__ lin1_w, const float* __restrict__ lin1_b,
                            const float* __restrict__ lin2_w, const float* __restrict__ lin2_b,
                            float* __restrict__ out) {
    const int g = blockIdx.x;
    const int lane = threadIdx.x;
    const float c = fmaxf((float)counts[g], 1.0f);
    const float p = pooled[g * 64 + lane] / c;
    float d1 = wave_reduce_sum(p * lin1_w[lane]);
    float d2 = wave_reduce_sum(p * lin2_w[lane]);
    if (lane == 0) {
        out[g] = d1 + lin1_b[0];
        out[N_GRAPHS + g] = d2 + lin2_b[0];
    }
}

// ---------------------------------------------------------------------------
extern "C" void kernel_launch(void* const* d_in, const int* in_sizes, int n_in,
                              void* d_out, int out_size, void* d_ws, size_t ws_size,
                              hipStream_t stream) {
    const float* x       = (const float*)d_in[0];
    const int*   ei      = (const int*)d_in[1];
    const int*   batch   = (const int*)d_in[2];
    const float* W1_rel  = (const float*)d_in[3];
    const float* W1_root = (const float*)d_in[4];
    const float* b1      = (const float*)d_in[5];
    const float* W2_rel  = (const float*)d_in[6];
    const float* W2_root = (const float*)d_in[7];
    const float* b2      = (const float*)d_in[8];
    const float* W3_rel  = (const float*)d_in[9];
    const float* W3_root = (const float*)d_in[10];
    const float* b3      = (const float*)d_in[11];
    const float* lin1_w  = (const float*)d_in[12];
    const float* lin1_b  = (const float*)d_in[13];
    const float* lin2_w  = (const float*)d_in[14];
    const float* lin2_b  = (const float*)d_in[15];

    const int N = in_sizes[0] / 3;       // 50000
    const int E = in_sizes[1] / 2;       // 800000
    const int* src = ei;
    const int* dst = ei + E;

    char* ws = (char*)d_ws;
    size_t off = 0;
    auto alloc = [&](size_t bytes) -> void* {
        void* p = ws + off;
        off += (bytes + 255) & ~(size_t)255;
        return p;
    };
    int* deg     = (int*)alloc((size_t)N * 4);
    int* rowptr  = (int*)alloc((size_t)(N + 1) * 4);
    int* cursor  = (int*)alloc((size_t)N * 4);
    int* csr_src = (int*)alloc((size_t)E * 4);
    int* partial = (int*)alloc(1024);
    int* boff    = (int*)alloc(1024);
    u16* bufA    = (u16*)alloc((size_t)N * HIDDEN * 2);
    u16* bufP    = (u16*)alloc((size_t)N * HIDDEN * 2);
    u16* bufB    = (u16*)alloc((size_t)N * HIDDEN * 2);
    u16* Bpk2    = (u16*)alloc(16 * 512 * 2);
    u16* Bpk3    = (u16*)alloc(16 * 512 * 2);
    float* pooled = (float*)alloc((size_t)N_GRAPHS * HIDDEN * 4);
    int* counts   = (int*)alloc((size_t)N_GRAPHS * 4);

    hipMemsetAsync(deg, 0, (size_t)N * 4, stream);
    hipMemsetAsync(pooled, 0, (size_t)N_GRAPHS * HIDDEN * 4, stream);
    hipMemsetAsync(counts, 0, (size_t)N_GRAPHS * 4, stream);

    const int eb = (E + 255) / 256;
    const int nb = (N + 255) / 256;
    degree_kernel<<<eb, 256, 0, stream>>>(dst, deg, E);
    scan_p1<<<nb, 256, 0, stream>>>(deg, partial, N);
    scan_p2<<<1, 256, 0, stream>>>(partial, boff, nb, rowptr, N, E);
    scan_p3<<<nb, 256, 0, stream>>>(deg, boff, rowptr, cursor, N);
    fill_kernel<<<eb, 256, 0, stream>>>(src, dst, cursor, csr_src, E);

    prepack_kernel<<<1, 1024, 0, stream>>>(W2_rel, W2_root, Bpk2);
    prepack_kernel<<<1, 1024, 0, stream>>>(W3_rel, W3_root, Bpk3);

    const int gb = (N + 7) / 8;          // gather: 2 nodes/wave, 8/block
    const int db = (N + 15) / 16;        // dense1: 4 nodes/wave, 16/block
    const int Ngrp = (N + 15) / 16;      // 16-node groups for MFMA dense
    const int mb = (Ngrp + 3) / 4;       // 4 waves/block

    dense1_kernel<<<db, 256, 0, stream>>>(x, W1_rel, W1_root, b1, bufP, bufB, N);
    gather_kernel<true ><<<gb, 256, 0, stream>>>(bufP, bufB, rowptr, csr_src, N);   // h1 in bufB
    dense_mfma_kernel<<<mb, 256, 0, stream>>>(bufB, Bpk2, b2, bufP, bufA, Ngrp);
    gather_kernel<true ><<<gb, 256, 0, stream>>>(bufP, bufA, rowptr, csr_src, N);   // h2 in bufA
    dense_mfma_kernel<<<mb, 256, 0, stream>>>(bufA, Bpk3, b3, bufP, bufB, Ngrp);
    gather_kernel<false><<<gb, 256, 0, stream>>>(bufP, bufB, rowptr, csr_src, N);   // h3 in bufB

    const int pool_waves = (N + 255) / 256;
    const int pool_blocks = (pool_waves + 3) / 4;
    pool_kernel<<<pool_blocks, 256, 0, stream>>>(bufB, batch, pooled, counts, N);
    head_kernel<<<N_GRAPHS, 64, 0, stream>>>(pooled, counts, lin1_w, lin1_b, lin2_w, lin2_b,
                                             (float*)d_out);
}

// Round 4
// 303.458 us; speedup vs baseline: 1.9608x; 1.1655x over previous
//
#include <hip/hip_runtime.h>

#define HIDDEN 64
#define N_GRAPHS 64

typedef unsigned int u32;
typedef unsigned short u16;

typedef __attribute__((ext_vector_type(8))) short short8;
typedef __attribute__((ext_vector_type(4))) float f32x4;

union U4S8 { uint4 u; short8 s; };
union U16x8 { u16 v[8]; uint4 u; };

// ---------------------------------------------------------------------------
// bf16 helpers
static __device__ __forceinline__ float bf_lo(u32 u) { return __uint_as_float(u << 16); }
static __device__ __forceinline__ float bf_hi(u32 u) { return __uint_as_float(u & 0xFFFF0000u); }
static __device__ __forceinline__ u16 f2bf(float f) {          // round-to-nearest-even
    u32 x = __float_as_uint(f);
    return (u16)((x + 0x7FFFu + ((x >> 16) & 1u)) >> 16);
}
static __device__ __forceinline__ u32 pack2(float a, float b) {
    return (u32)f2bf(a) | ((u32)f2bf(b) << 16);
}

static __device__ __forceinline__ float wave_reduce_sum(float v) {
    for (int off = 32; off; off >>= 1) v += __shfl_xor(v, off, 64);
    return v;
}

// ---------------------------------------------------------------------------
// CSR build
__global__ void degree_kernel(const int* __restrict__ dst, int* __restrict__ deg, int E) {
    int e = blockIdx.x * blockDim.x + threadIdx.x;
    if (e < E) atomicAdd(&deg[dst[e]], 1);
}

__global__ void scan_p1(const int* __restrict__ deg, int* __restrict__ partial, int N) {
    __shared__ int s[256];
    const int t = threadIdx.x, i = blockIdx.x * 256 + t;
    s[t] = (i < N) ? deg[i] : 0;
    __syncthreads();
    for (int off = 128; off; off >>= 1) {
        if (t < off) s[t] += s[t + off];
        __syncthreads();
    }
    if (t == 0) partial[blockIdx.x] = s[0];
}

__global__ void scan_p2(const int* __restrict__ partial, int* __restrict__ boff,
                        int nb, int* __restrict__ rowptr, int N, int E) {
    __shared__ int s[256];
    const int t = threadIdx.x;
    int carry = 0;
    for (int base = 0; base < nb; base += 256) {
        int v = (base + t < nb) ? partial[base + t] : 0;
        s[t] = v;
        __syncthreads();
        for (int off = 1; off < 256; off <<= 1) {
            int u = (t >= off) ? s[t - off] : 0;
            __syncthreads();
            s[t] += u;
            __syncthreads();
        }
        if (base + t < nb) boff[base + t] = carry + s[t] - v;
        int tot = s[255];
        __syncthreads();
        carry += tot;
    }
    if (t == 0) rowptr[N] = E;
}

// also seeds cursor = rowptr so fill needs no separate rowptr load/memset
__global__ void scan_p3(const int* __restrict__ deg, const int* __restrict__ boff,
                        int* __restrict__ rowptr, int* __restrict__ cursor, int N) {
    __shared__ int s[256];
    const int t = threadIdx.x, i = blockIdx.x * 256 + t;
    int v = (i < N) ? deg[i] : 0;
    s[t] = v;
    __syncthreads();
    for (int off = 1; off < 256; off <<= 1) {
        int u = (t >= off) ? s[t - off] : 0;
        __syncthreads();
        s[t] += u;
        __syncthreads();
    }
    if (i < N) {
        int rp = boff[blockIdx.x] + s[t] - v;
        rowptr[i] = rp;
        cursor[i] = rp;
    }
}

__global__ void fill_kernel(const int* __restrict__ src, const int* __restrict__ dst,
                            int* __restrict__ cursor, int* __restrict__ csr_src, int E) {
    int e = blockIdx.x * blockDim.x + threadIdx.x;
    if (e >= E) return;
    int slot = atomicAdd(&cursor[dst[e]], 1);   // cursor pre-seeded with rowptr
    csr_src[slot] = src[e];
}

// ---------------------------------------------------------------------------
// dense1: P = x@W1_rel, R = x@W1_root + b1   (IN_DIM=3, outputs bf16)
__global__ __launch_bounds__(256) void dense1_kernel(
        const float* __restrict__ x, const float* __restrict__ Wrel,
        const float* __restrict__ Wroot, const float* __restrict__ bias,
        u16* __restrict__ P, u16* __restrict__ R, int N) {
    const int lane = threadIdx.x & 63;
    const int gw = (blockIdx.x * 256 + threadIdx.x) >> 6;
    const int n0 = gw * 4;
    if (n0 >= N) return;
    const float wr0 = Wrel[lane], wr1 = Wrel[64 + lane], wr2 = Wrel[128 + lane];
    const float wo0 = Wroot[lane], wo1 = Wroot[64 + lane], wo2 = Wroot[128 + lane];
    const float bb = bias[lane];
    const int n1 = min(n0 + 4, N);
    for (int n = n0; n < n1; ++n) {
        const float x0 = x[n * 3 + 0], x1 = x[n * 3 + 1], x2 = x[n * 3 + 2];
        const float p = x0 * wr0 + x1 * wr1 + x2 * wr2;
        const float r = x0 * wo0 + x1 * wo1 + x2 * wo2 + bb;
        P[(size_t)n * 64 + lane] = f2bf(p);
        R[(size_t)n * 64 + lane] = f2bf(r);
    }
}

// ---------------------------------------------------------------------------
// Prepack W = [Wrel | Wroot] (64K x 128N) into MFMA B-fragment lane order.
__global__ void prepack_kernel(const float* __restrict__ Wrel,
                               const float* __restrict__ Wroot,
                               u16* __restrict__ Bpk) {
    const int tid = threadIdx.x;            // 1024 threads
    const int f = tid >> 6, l = tid & 63;
    const int t = f >> 1, kc = f & 1;
    const int kb = kc * 32 + (l >> 4) * 8;
    const int n = t * 16 + (l & 15);
    U16x8 o;
    #pragma unroll
    for (int j = 0; j < 8; ++j) {
        const int k = kb + j;
        const float w = (n < 64) ? Wrel[k * 64 + n] : Wroot[k * 64 + (n - 64)];
        o.v[j] = f2bf(w);
    }
    ((uint4*)Bpk)[tid] = o.u;
}

// ---------------------------------------------------------------------------
// dense (64->64): [16 nodes x 64] @ [64 x 128] per wave via 16 MFMAs.
__global__ __launch_bounds__(256) void dense_mfma_kernel(
        const u16* __restrict__ h_in, const u16* __restrict__ Bpk,
        const float* __restrict__ bias, u16* __restrict__ P, u16* __restrict__ R,
        int Ngrp) {
    const int lane = threadIdx.x & 63;
    const int wid = (blockIdx.x * 256 + threadIdx.x) >> 6;
    if (wid >= Ngrp) return;

    U4S8 bf[16];
    const uint4* bp = (const uint4*)Bpk;
    #pragma unroll
    for (int f = 0; f < 16; ++f) bf[f].u = bp[f * 64 + lane];

    const int n0 = wid * 16;
    const int row = lane & 15, quad = lane >> 4;
    const u16* arow = h_in + (size_t)(n0 + row) * 64 + quad * 8;
    U4S8 a0, a1;
    a0.u = *(const uint4*)(arow);
    a1.u = *(const uint4*)(arow + 32);

    f32x4 acc[8];
    #pragma unroll
    for (int t = 0; t < 8; ++t) {
        f32x4 z = {0.f, 0.f, 0.f, 0.f};
        z = __builtin_amdgcn_mfma_f32_16x16x32_bf16(a0.s, bf[t * 2 + 0].s, z, 0, 0, 0);
        acc[t] = __builtin_amdgcn_mfma_f32_16x16x32_bf16(a1.s, bf[t * 2 + 1].s, z, 0, 0, 0);
    }

    const int col = lane & 15;
    #pragma unroll
    for (int t = 0; t < 4; ++t) {
        #pragma unroll
        for (int r = 0; r < 4; ++r) {
            const int node = n0 + quad * 4 + r;
            P[(size_t)node * 64 + t * 16 + col] = f2bf(acc[t][r]);
        }
    }
    #pragma unroll
    for (int t = 0; t < 4; ++t) {
        const float bb = bias[t * 16 + col];
        #pragma unroll
        for (int r = 0; r < 4; ++r) {
            const int node = n0 + quad * 4 + r;
            R[(size_t)node * 64 + t * 16 + col] = f2bf(acc[4 + t][r] + bb);
        }
    }
}

// ---------------------------------------------------------------------------
// gather: h_out[i] = act( sum_{j->i} P[j] + R[i] ).  One wave per node,
// 8 lane-groups x 16B -> 8 neighbor rows per load instr, unrolled x2.
template <bool RELU>
__global__ __launch_bounds__(256) void gather_kernel(
        const u16* __restrict__ P, u16* __restrict__ R_h,
        const int* __restrict__ rowptr, const int* __restrict__ csr_src, int N) {
    const int lane = threadIdx.x & 63;
    const int grp = lane >> 3;       // neighbor slot within round
    const int c = lane & 7;          // 16B chunk within row (8 bf16 channels)
    const int node = (blockIdx.x * 256 + threadIdx.x) >> 6;
    if (node >= N) return;
    const int start = rowptr[node];
    const int deg = rowptr[node + 1] - start;

    float acc[8] = {0.f, 0.f, 0.f, 0.f, 0.f, 0.f, 0.f, 0.f};

    for (int base = 0; base < deg; base += 64) {
        const int m = min(64, deg - base);
        int jreg = (lane < m) ? csr_src[start + base + lane] : 0;
        int r = 0;
        for (; r + 16 <= m; r += 16) {
            const int j0 = __shfl(jreg, r + grp, 64);
            const int j1 = __shfl(jreg, r + 8 + grp, 64);
            const uint4 v0 = *((const uint4*)(P + (size_t)j0 * 64) + c);
            const uint4 v1 = *((const uint4*)(P + (size_t)j1 * 64) + c);
            acc[0] += bf_lo(v0.x); acc[1] += bf_hi(v0.x);
            acc[2] += bf_lo(v0.y); acc[3] += bf_hi(v0.y);
            acc[4] += bf_lo(v0.z); acc[5] += bf_hi(v0.z);
            acc[6] += bf_lo(v0.w); acc[7] += bf_hi(v0.w);
            acc[0] += bf_lo(v1.x); acc[1] += bf_hi(v1.x);
            acc[2] += bf_lo(v1.y); acc[3] += bf_hi(v1.y);
            acc[4] += bf_lo(v1.z); acc[5] += bf_hi(v1.z);
            acc[6] += bf_lo(v1.w); acc[7] += bf_hi(v1.w);
        }
        for (; r < m; r += 8) {
            const int srcl = r + grp;
            const int j = __shfl(jreg, srcl, 64);
            if (srcl < m) {
                const uint4 v = *((const uint4*)(P + (size_t)j * 64) + c);
                acc[0] += bf_lo(v.x); acc[1] += bf_hi(v.x);
                acc[2] += bf_lo(v.y); acc[3] += bf_hi(v.y);
                acc[4] += bf_lo(v.z); acc[5] += bf_hi(v.z);
                acc[6] += bf_lo(v.w); acc[7] += bf_hi(v.w);
            }
        }
    }
    #pragma unroll
    for (int off = 8; off <= 32; off <<= 1) {
        #pragma unroll
        for (int i = 0; i < 8; ++i) acc[i] += __shfl_xor(acc[i], off, 64);
    }
    if (lane < 8) {
        const uint4 rv = *((const uint4*)(R_h + (size_t)node * 64) + lane);
        float o[8];
        o[0] = acc[0] + bf_lo(rv.x); o[1] = acc[1] + bf_hi(rv.x);
        o[2] = acc[2] + bf_lo(rv.y); o[3] = acc[3] + bf_hi(rv.y);
        o[4] = acc[4] + bf_lo(rv.z); o[5] = acc[5] + bf_hi(rv.z);
        o[6] = acc[6] + bf_lo(rv.w); o[7] = acc[7] + bf_hi(rv.w);
        if (RELU) {
            #pragma unroll
            for (int i = 0; i < 8; ++i) o[i] = fmaxf(o[i], 0.f);
        }
        uint4 sv;
        sv.x = pack2(o[0], o[1]); sv.y = pack2(o[2], o[3]);
        sv.z = pack2(o[4], o[5]); sv.w = pack2(o[6], o[7]);
        *((uint4*)(R_h + (size_t)node * 64) + lane) = sv;
    }
}

// ---------------------------------------------------------------------------
// Global mean pool, parallel version: 32 nodes per wave, 8 rows per round
// (grp = lane>>3 picks the row, c = lane&7 picks the 16B chunk).  Register
// accumulation; flush on graph transitions (batch is sorted, 63 boundaries
// globally).  Mixed-graph rounds fall back to direct atomics (rare).
__global__ __launch_bounds__(256) void pool_kernel(
        const u16* __restrict__ h, const int* __restrict__ batch,
        float* __restrict__ pooled, int* __restrict__ counts, int N) {
    const int lane = threadIdx.x & 63;
    const int grp = lane >> 3, c = lane & 7;
    const int wid = (blockIdx.x * 256 + threadIdx.x) >> 6;
    const int base0 = wid * 32;
    if (base0 >= N) return;
    const int base1 = min(base0 + 32, N);

    float acc[8] = {0.f, 0.f, 0.f, 0.f, 0.f, 0.f, 0.f, 0.f};
    int cnt = 0;
    int g_cur = batch[base0];

    for (int base = base0; base < base1; base += 8) {
        const int n = base + grp;
        const bool valid = (n < base1);
        const int gl = valid ? batch[n] : -1;
        uint4 v = make_uint4(0, 0, 0, 0);
        if (valid) v = *((const uint4*)(h + (size_t)n * 64) + c);
        const bool uni = __all((!valid) || (gl == g_cur));
        if (uni) {
            acc[0] += bf_lo(v.x); acc[1] += bf_hi(v.x);
            acc[2] += bf_lo(v.y); acc[3] += bf_hi(v.y);
            acc[4] += bf_lo(v.z); acc[5] += bf_hi(v.z);
            acc[6] += bf_lo(v.w); acc[7] += bf_hi(v.w);
            cnt += min(8, base1 - base);
        } else {
            // flush current accumulator for g_cur
            float t[8];
            #pragma unroll
            for (int i = 0; i < 8; ++i) t[i] = acc[i];
            #pragma unroll
            for (int off = 8; off <= 32; off <<= 1) {
                #pragma unroll
                for (int i = 0; i < 8; ++i) t[i] += __shfl_xor(t[i], off, 64);
            }
            if (lane < 8) {
                #pragma unroll
                for (int i = 0; i < 8; ++i)
                    atomicAdd(&pooled[g_cur * 64 + lane * 8 + i], t[i]);
            }
            if (lane == 0) atomicAdd(&counts[g_cur], cnt);
            #pragma unroll
            for (int i = 0; i < 8; ++i) acc[i] = 0.f;
            cnt = 0;
            // mixed round: direct atomics per lane
            if (valid) {
                atomicAdd(&pooled[gl * 64 + c * 8 + 0], bf_lo(v.x));
                atomicAdd(&pooled[gl * 64 + c * 8 + 1], bf_hi(v.x));
                atomicAdd(&pooled[gl * 64 + c * 8 + 2], bf_lo(v.y));
                atomicAdd(&pooled[gl * 64 + c * 8 + 3], bf_hi(v.y));
                atomicAdd(&pooled[gl * 64 + c * 8 + 4], bf_lo(v.z));
                atomicAdd(&pooled[gl * 64 + c * 8 + 5], bf_hi(v.z));
                atomicAdd(&pooled[gl * 64 + c * 8 + 6], bf_lo(v.w));
                atomicAdd(&pooled[gl * 64 + c * 8 + 7], bf_hi(v.w));
                if (c == 0) atomicAdd(&counts[gl], 1);
            }
            g_cur = __shfl(gl, 56, 64);   // graph of the last row this round
        }
    }
    if (cnt > 0 && g_cur >= 0) {
        #pragma unroll
        for (int off = 8; off <= 32; off <<= 1) {
            #pragma unroll
            for (int i = 0; i < 8; ++i) acc[i] += __shfl_xor(acc[i], off, 64);
        }
        if (lane < 8) {
            #pragma unroll
            for (int i = 0; i < 8; ++i)
                atomicAdd(&pooled[g_cur * 64 + lane * 8 + i], acc[i]);
        }
        if (lane == 0) atomicAdd(&counts[g_cur], cnt);
    }
}

__global__ void head_kernel(const float* __restrict__ pooled, const int* __restrict__ counts,
                            const float* __restrict__ lin1_w, const float* __restrict__ lin1_b,
                            const float* __restrict__ lin2_w, const float* __restrict__ lin2_b,
                            float* __restrict__ out) {
    const int g = blockIdx.x;
    const int lane = threadIdx.x;
    const float c = fmaxf((float)counts[g], 1.0f);
    const float p = pooled[g * 64 + lane] / c;
    float d1 = wave_reduce_sum(p * lin1_w[lane]);
    float d2 = wave_reduce_sum(p * lin2_w[lane]);
    if (lane == 0) {
        out[g] = d1 + lin1_b[0];
        out[N_GRAPHS + g] = d2 + lin2_b[0];
    }
}

// ---------------------------------------------------------------------------
extern "C" void kernel_launch(void* const* d_in, const int* in_sizes, int n_in,
                              void* d_out, int out_size, void* d_ws, size_t ws_size,
                              hipStream_t stream) {
    const float* x       = (const float*)d_in[0];
    const int*   ei      = (const int*)d_in[1];
    const int*   batch   = (const int*)d_in[2];
    const float* W1_rel  = (const float*)d_in[3];
    const float* W1_root = (const float*)d_in[4];
    const float* b1      = (const float*)d_in[5];
    const float* W2_rel  = (const float*)d_in[6];
    const float* W2_root = (const float*)d_in[7];
    const float* b2      = (const float*)d_in[8];
    const float* W3_rel  = (const float*)d_in[9];
    const float* W3_root = (const float*)d_in[10];
    const float* b3      = (const float*)d_in[11];
    const float* lin1_w  = (const float*)d_in[12];
    const float* lin1_b  = (const float*)d_in[13];
    const float* lin2_w  = (const float*)d_in[14];
    const float* lin2_b  = (const float*)d_in[15];

    const int N = in_sizes[0] / 3;       // 50000
    const int E = in_sizes[1] / 2;       // 800000
    const int* src = ei;
    const int* dst = ei + E;

    char* ws = (char*)d_ws;
    size_t off = 0;
    auto alloc = [&](size_t bytes) -> void* {
        void* p = ws + off;
        off += (bytes + 255) & ~(size_t)255;
        return p;
    };
    int* deg     = (int*)alloc((size_t)N * 4);
    int* rowptr  = (int*)alloc((size_t)(N + 1) * 4);
    int* cursor  = (int*)alloc((size_t)N * 4);
    int* csr_src = (int*)alloc((size_t)E * 4);
    int* partial = (int*)alloc(1024);
    int* boff    = (int*)alloc(1024);
    u16* bufA    = (u16*)alloc((size_t)N * HIDDEN * 2);
    u16* bufP    = (u16*)alloc((size_t)N * HIDDEN * 2);
    u16* bufB    = (u16*)alloc((size_t)N * HIDDEN * 2);
    u16* Bpk2    = (u16*)alloc(16 * 512 * 2);
    u16* Bpk3    = (u16*)alloc(16 * 512 * 2);
    float* pooled = (float*)alloc((size_t)N_GRAPHS * HIDDEN * 4);
    int* counts   = (int*)alloc((size_t)N_GRAPHS * 4);

    hipMemsetAsync(deg, 0, (size_t)N * 4, stream);
    hipMemsetAsync(pooled, 0, (size_t)N_GRAPHS * HIDDEN * 4, stream);
    hipMemsetAsync(counts, 0, (size_t)N_GRAPHS * 4, stream);

    const int eb = (E + 255) / 256;
    const int nb = (N + 255) / 256;
    degree_kernel<<<eb, 256, 0, stream>>>(dst, deg, E);
    scan_p1<<<nb, 256, 0, stream>>>(deg, partial, N);
    scan_p2<<<1, 256, 0, stream>>>(partial, boff, nb, rowptr, N, E);
    scan_p3<<<nb, 256, 0, stream>>>(deg, boff, rowptr, cursor, N);
    fill_kernel<<<eb, 256, 0, stream>>>(src, dst, cursor, csr_src, E);

    prepack_kernel<<<1, 1024, 0, stream>>>(W2_rel, W2_root, Bpk2);
    prepack_kernel<<<1, 1024, 0, stream>>>(W3_rel, W3_root, Bpk3);

    const int gb = (N + 3) / 4;          // gather: 1 node/wave, 4/block
    const int db = (N + 15) / 16;        // dense1: 4 nodes/wave, 16/block
    const int Ngrp = (N + 15) / 16;      // 16-node groups for MFMA dense
    const int mb = (Ngrp + 3) / 4;       // 4 waves/block

    dense1_kernel<<<db, 256, 0, stream>>>(x, W1_rel, W1_root, b1, bufP, bufB, N);
    gather_kernel<true ><<<gb, 256, 0, stream>>>(bufP, bufB, rowptr, csr_src, N);   // h1 in bufB
    dense_mfma_kernel<<<mb, 256, 0, stream>>>(bufB, Bpk2, b2, bufP, bufA, Ngrp);
    gather_kernel<true ><<<gb, 256, 0, stream>>>(bufP, bufA, rowptr, csr_src, N);   // h2 in bufA
    dense_mfma_kernel<<<mb, 256, 0, stream>>>(bufA, Bpk3, b3, bufP, bufB, Ngrp);
    gather_kernel<false><<<gb, 256, 0, stream>>>(bufP, bufB, rowptr, csr_src, N);   // h3 in bufB

    const int pool_waves = (N + 31) / 32;
    const int pool_blocks = (pool_waves + 3) / 4;
    pool_kernel<<<pool_blocks, 256, 0, stream>>>(bufB, batch, pooled, counts, N);
    head_kernel<<<N_GRAPHS, 64, 0, stream>>>(pooled, counts, lin1_w, lin1_b, lin2_w, lin2_b,
                                             (float*)d_out);
}

// Round 5
// 245.686 us; speedup vs baseline: 2.4218x; 1.2351x over previous
//
#include <hip/hip_runtime.h>

#define HIDDEN 64
#define N_GRAPHS 64
#define NBMAX 1024            // max coarse buckets (N <= 65536)

typedef unsigned int u32;
typedef unsigned short u16;

typedef __attribute__((ext_vector_type(8))) short short8;
typedef __attribute__((ext_vector_type(4))) float f32x4;

union U4S8 { uint4 u; short8 s; };
union U16x8 { u16 v[8]; uint4 u; };

// ---------------------------------------------------------------------------
// bf16 helpers
static __device__ __forceinline__ float bf_lo(u32 u) { return __uint_as_float(u << 16); }
static __device__ __forceinline__ float bf_hi(u32 u) { return __uint_as_float(u & 0xFFFF0000u); }
static __device__ __forceinline__ u16 f2bf(float f) {          // round-to-nearest-even
    u32 x = __float_as_uint(f);
    return (u16)((x + 0x7FFFu + ((x >> 16) & 1u)) >> 16);
}
static __device__ __forceinline__ u32 pack2(float a, float b) {
    return (u32)f2bf(a) | ((u32)f2bf(b) << 16);
}

static __device__ __forceinline__ float wave_reduce_sum(float v) {
    for (int off = 32; off; off >>= 1) v += __shfl_xor(v, off, 64);
    return v;
}

// ---------------------------------------------------------------------------
// CSR build via 2-level counting sort by dst.
// Buckets: b = dst >> 6 (64 nodes per bucket). src,dst < 65536 so an edge
// packs into u32 = (localdst << 16) | src.

// A: coarse bucket histogram (LDS-privatized, few global atomics)
__global__ __launch_bounds__(256) void hist_kernel(
        const int* __restrict__ dst, u32* __restrict__ hist_g, int E, int NB) {
    __shared__ u32 lh[NBMAX];
    const int tid = threadIdx.x;
    for (int i = tid; i < NB; i += 256) lh[i] = 0;
    __syncthreads();
    const int stride = gridDim.x * 256;
    for (int e = blockIdx.x * 256 + tid; e < E; e += stride)
        atomicAdd(&lh[dst[e] >> 6], 1u);
    __syncthreads();
    for (int i = tid; i < NB; i += 256)
        if (lh[i]) atomicAdd(&hist_g[i], lh[i]);
}

// B: exclusive scan of bucket counts -> boff[0..NB], cursor copy, rowptr[N]=E
__global__ __launch_bounds__(1024) void bscan_kernel(
        const u32* __restrict__ hist_g, u32* __restrict__ boff,
        u32* __restrict__ cursor_g, int* __restrict__ rowptr, int NB, int N, int E) {
    __shared__ u32 s[NBMAX];
    const int t = threadIdx.x;
    u32 v = (t < NB) ? hist_g[t] : 0;
    s[t] = v;
    __syncthreads();
    for (int off = 1; off < 1024; off <<= 1) {
        u32 u = (t >= off) ? s[t - off] : 0;
        __syncthreads();
        s[t] += u;
        __syncthreads();
    }
    if (t < NB) {
        u32 ex = s[t] - v;
        boff[t] = ex;
        cursor_g[t] = ex;
    }
    if (t == 0) { boff[NB] = (u32)E; rowptr[N] = E; }
}

// C: partition edges into bucket regions.  Per-block LDS histogram + one
// global reservation atomic per (block,bucket); packed u32 edge writes.
__global__ __launch_bounds__(256) void partition_kernel(
        const int* __restrict__ src, const int* __restrict__ dst,
        u32* __restrict__ cursor_g, u32* __restrict__ ebuf, int E, int NB, int K) {
    __shared__ u32 lh[NBMAX];
    __shared__ u32 res[NBMAX];
    const int tid = threadIdx.x;
    const int e0 = blockIdx.x * K;
    const int e1 = min(e0 + K, E);
    for (int i = tid; i < NB; i += 256) lh[i] = 0;
    __syncthreads();
    for (int e = e0 + tid; e < e1; e += 256)
        atomicAdd(&lh[dst[e] >> 6], 1u);
    __syncthreads();
    for (int i = tid; i < NB; i += 256) {
        const u32 c = lh[i];
        if (c) res[i] = atomicAdd(&cursor_g[i], c);
    }
    __syncthreads();
    for (int e = e0 + tid; e < e1; e += 256) {
        const int d = dst[e];
        const u32 p = atomicAdd(&res[d >> 6], 1u);
        ebuf[p] = ((u32)(d & 63) << 16) | (u32)src[e];
    }
}

// D: per-bucket (one block, single XCD owns the output region): per-node
// histogram -> rowptr, then scatter csr_src (lines fully written locally).
__global__ __launch_bounds__(256) void bucket_kernel(
        const u32* __restrict__ boff, const u32* __restrict__ ebuf,
        int* __restrict__ rowptr, int* __restrict__ csr_src, int N) {
    __shared__ u32 h64[64];
    __shared__ u32 cur[64];
    const int b = blockIdx.x;
    const int tid = threadIdx.x;
    const u32 base = boff[b];
    const u32 end = boff[b + 1];
    if (tid < 64) h64[tid] = 0;
    __syncthreads();
    for (u32 i = base + tid; i < end; i += 256)
        atomicAdd(&h64[ebuf[i] >> 16], 1u);
    __syncthreads();
    if (tid == 0) {                       // serial 64-entry exclusive scan
        u32 run = base;
        #pragma unroll
        for (int i = 0; i < 64; ++i) {
            cur[i] = run;
            run += h64[i];
        }
    }
    __syncthreads();
    if (tid < 64) {
        const int node = b * 64 + tid;
        if (node < N) rowptr[node] = (int)cur[tid];
    }
    __syncthreads();
    for (u32 i = base + tid; i < end; i += 256) {
        const u32 v = ebuf[i];
        const u32 p = atomicAdd(&cur[v >> 16], 1u);
        csr_src[p] = (int)(v & 0xFFFFu);
    }
}

// ---------------------------------------------------------------------------
// dense1: P = x@W1_rel, R = x@W1_root + b1   (IN_DIM=3, outputs bf16)
__global__ __launch_bounds__(256) void dense1_kernel(
        const float* __restrict__ x, const float* __restrict__ Wrel,
        const float* __restrict__ Wroot, const float* __restrict__ bias,
        u16* __restrict__ P, u16* __restrict__ R, int N) {
    const int lane = threadIdx.x & 63;
    const int gw = (blockIdx.x * 256 + threadIdx.x) >> 6;
    const int n0 = gw * 4;
    if (n0 >= N) return;
    const float wr0 = Wrel[lane], wr1 = Wrel[64 + lane], wr2 = Wrel[128 + lane];
    const float wo0 = Wroot[lane], wo1 = Wroot[64 + lane], wo2 = Wroot[128 + lane];
    const float bb = bias[lane];
    const int n1 = min(n0 + 4, N);
    for (int n = n0; n < n1; ++n) {
        const float x0 = x[n * 3 + 0], x1 = x[n * 3 + 1], x2 = x[n * 3 + 2];
        const float p = x0 * wr0 + x1 * wr1 + x2 * wr2;
        const float r = x0 * wo0 + x1 * wo1 + x2 * wo2 + bb;
        P[(size_t)n * 64 + lane] = f2bf(p);
        R[(size_t)n * 64 + lane] = f2bf(r);
    }
}

// ---------------------------------------------------------------------------
// Prepack W = [Wrel | Wroot] (64K x 128N) into MFMA B-fragment lane order.
// blockIdx.x selects layer (0 -> W2/Bpk2, 1 -> W3/Bpk3).
__global__ void prepack_kernel(const float* __restrict__ W2rel, const float* __restrict__ W2root,
                               const float* __restrict__ W3rel, const float* __restrict__ W3root,
                               u16* __restrict__ Bpk2, u16* __restrict__ Bpk3) {
    const float* Wrel  = blockIdx.x ? W3rel : W2rel;
    const float* Wroot = blockIdx.x ? W3root : W2root;
    u16* Bpk = blockIdx.x ? Bpk3 : Bpk2;
    const int tid = threadIdx.x;            // 1024 threads
    const int f = tid >> 6, l = tid & 63;
    const int t = f >> 1, kc = f & 1;
    const int kb = kc * 32 + (l >> 4) * 8;
    const int n = t * 16 + (l & 15);
    U16x8 o;
    #pragma unroll
    for (int j = 0; j < 8; ++j) {
        const int k = kb + j;
        const float w = (n < 64) ? Wrel[k * 64 + n] : Wroot[k * 64 + (n - 64)];
        o.v[j] = f2bf(w);
    }
    ((uint4*)Bpk)[tid] = o.u;
}

// ---------------------------------------------------------------------------
// dense (64->64): [16 nodes x 64] @ [64 x 128] per wave via 16 MFMAs.
__global__ __launch_bounds__(256) void dense_mfma_kernel(
        const u16* __restrict__ h_in, const u16* __restrict__ Bpk,
        const float* __restrict__ bias, u16* __restrict__ P, u16* __restrict__ R,
        int Ngrp) {
    const int lane = threadIdx.x & 63;
    const int wid = (blockIdx.x * 256 + threadIdx.x) >> 6;
    if (wid >= Ngrp) return;

    U4S8 bf[16];
    const uint4* bp = (const uint4*)Bpk;
    #pragma unroll
    for (int f = 0; f < 16; ++f) bf[f].u = bp[f * 64 + lane];

    const int n0 = wid * 16;
    const int row = lane & 15, quad = lane >> 4;
    const u16* arow = h_in + (size_t)(n0 + row) * 64 + quad * 8;
    U4S8 a0, a1;
    a0.u = *(const uint4*)(arow);
    a1.u = *(const uint4*)(arow + 32);

    f32x4 acc[8];
    #pragma unroll
    for (int t = 0; t < 8; ++t) {
        f32x4 z = {0.f, 0.f, 0.f, 0.f};
        z = __builtin_amdgcn_mfma_f32_16x16x32_bf16(a0.s, bf[t * 2 + 0].s, z, 0, 0, 0);
        acc[t] = __builtin_amdgcn_mfma_f32_16x16x32_bf16(a1.s, bf[t * 2 + 1].s, z, 0, 0, 0);
    }

    const int col = lane & 15;
    #pragma unroll
    for (int t = 0; t < 4; ++t) {
        #pragma unroll
        for (int r = 0; r < 4; ++r) {
            const int node = n0 + quad * 4 + r;
            P[(size_t)node * 64 + t * 16 + col] = f2bf(acc[t][r]);
        }
    }
    #pragma unroll
    for (int t = 0; t < 4; ++t) {
        const float bb = bias[t * 16 + col];
        #pragma unroll
        for (int r = 0; r < 4; ++r) {
            const int node = n0 + quad * 4 + r;
            R[(size_t)node * 64 + t * 16 + col] = f2bf(acc[4 + t][r] + bb);
        }
    }
}

// ---------------------------------------------------------------------------
// gather: h_out[i] = act( sum_{j->i} P[j] + R[i] ).  One wave per node,
// 8 lane-groups x 16B -> 8 neighbor rows per load instr, unrolled x2.
template <bool RELU>
__global__ __launch_bounds__(256) void gather_kernel(
        const u16* __restrict__ P, u16* __restrict__ R_h,
        const int* __restrict__ rowptr, const int* __restrict__ csr_src, int N) {
    const int lane = threadIdx.x & 63;
    const int grp = lane >> 3;       // neighbor slot within round
    const int c = lane & 7;          // 16B chunk within row (8 bf16 channels)
    const int node = (blockIdx.x * 256 + threadIdx.x) >> 6;
    if (node >= N) return;
    const int start = rowptr[node];
    const int deg = rowptr[node + 1] - start;

    float acc[8] = {0.f, 0.f, 0.f, 0.f, 0.f, 0.f, 0.f, 0.f};

    for (int base = 0; base < deg; base += 64) {
        const int m = min(64, deg - base);
        int jreg = (lane < m) ? csr_src[start + base + lane] : 0;
        int r = 0;
        for (; r + 16 <= m; r += 16) {
            const int j0 = __shfl(jreg, r + grp, 64);
            const int j1 = __shfl(jreg, r + 8 + grp, 64);
            const uint4 v0 = *((const uint4*)(P + (size_t)j0 * 64) + c);
            const uint4 v1 = *((const uint4*)(P + (size_t)j1 * 64) + c);
            acc[0] += bf_lo(v0.x); acc[1] += bf_hi(v0.x);
            acc[2] += bf_lo(v0.y); acc[3] += bf_hi(v0.y);
            acc[4] += bf_lo(v0.z); acc[5] += bf_hi(v0.z);
            acc[6] += bf_lo(v0.w); acc[7] += bf_hi(v0.w);
            acc[0] += bf_lo(v1.x); acc[1] += bf_hi(v1.x);
            acc[2] += bf_lo(v1.y); acc[3] += bf_hi(v1.y);
            acc[4] += bf_lo(v1.z); acc[5] += bf_hi(v1.z);
            acc[6] += bf_lo(v1.w); acc[7] += bf_hi(v1.w);
        }
        for (; r < m; r += 8) {
            const int srcl = r + grp;
            const int j = __shfl(jreg, srcl, 64);
            if (srcl < m) {
                const uint4 v = *((const uint4*)(P + (size_t)j * 64) + c);
                acc[0] += bf_lo(v.x); acc[1] += bf_hi(v.x);
                acc[2] += bf_lo(v.y); acc[3] += bf_hi(v.y);
                acc[4] += bf_lo(v.z); acc[5] += bf_hi(v.z);
                acc[6] += bf_lo(v.w); acc[7] += bf_hi(v.w);
            }
        }
    }
    #pragma unroll
    for (int off = 8; off <= 32; off <<= 1) {
        #pragma unroll
        for (int i = 0; i < 8; ++i) acc[i] += __shfl_xor(acc[i], off, 64);
    }
    if (lane < 8) {
        const uint4 rv = *((const uint4*)(R_h + (size_t)node * 64) + lane);
        float o[8];
        o[0] = acc[0] + bf_lo(rv.x); o[1] = acc[1] + bf_hi(rv.x);
        o[2] = acc[2] + bf_lo(rv.y); o[3] = acc[3] + bf_hi(rv.y);
        o[4] = acc[4] + bf_lo(rv.z); o[5] = acc[5] + bf_hi(rv.z);
        o[6] = acc[6] + bf_lo(rv.w); o[7] = acc[7] + bf_hi(rv.w);
        if (RELU) {
            #pragma unroll
            for (int i = 0; i < 8; ++i) o[i] = fmaxf(o[i], 0.f);
        }
        uint4 sv;
        sv.x = pack2(o[0], o[1]); sv.y = pack2(o[2], o[3]);
        sv.z = pack2(o[4], o[5]); sv.w = pack2(o[6], o[7]);
        *((uint4*)(R_h + (size_t)node * 64) + lane) = sv;
    }
}

// ---------------------------------------------------------------------------
// Global mean pool: 32 nodes per wave, register accumulation, flush on
// graph transitions (batch sorted, 63 boundaries).
__global__ __launch_bounds__(256) void pool_kernel(
        const u16* __restrict__ h, const int* __restrict__ batch,
        float* __restrict__ pooled, int* __restrict__ counts, int N) {
    const int lane = threadIdx.x & 63;
    const int grp = lane >> 3, c = lane & 7;
    const int wid = (blockIdx.x * 256 + threadIdx.x) >> 6;
    const int base0 = wid * 32;
    if (base0 >= N) return;
    const int base1 = min(base0 + 32, N);

    float acc[8] = {0.f, 0.f, 0.f, 0.f, 0.f, 0.f, 0.f, 0.f};
    int cnt = 0;
    int g_cur = batch[base0];

    for (int base = base0; base < base1; base += 8) {
        const int n = base + grp;
        const bool valid = (n < base1);
        const int gl = valid ? batch[n] : -1;
        uint4 v = make_uint4(0, 0, 0, 0);
        if (valid) v = *((const uint4*)(h + (size_t)n * 64) + c);
        const bool uni = __all((!valid) || (gl == g_cur));
        if (uni) {
            acc[0] += bf_lo(v.x); acc[1] += bf_hi(v.x);
            acc[2] += bf_lo(v.y); acc[3] += bf_hi(v.y);
            acc[4] += bf_lo(v.z); acc[5] += bf_hi(v.z);
            acc[6] += bf_lo(v.w); acc[7] += bf_hi(v.w);
            cnt += min(8, base1 - base);
        } else {
            float t[8];
            #pragma unroll
            for (int i = 0; i < 8; ++i) t[i] = acc[i];
            #pragma unroll
            for (int off = 8; off <= 32; off <<= 1) {
                #pragma unroll
                for (int i = 0; i < 8; ++i) t[i] += __shfl_xor(t[i], off, 64);
            }
            if (lane < 8) {
                #pragma unroll
                for (int i = 0; i < 8; ++i)
                    atomicAdd(&pooled[g_cur * 64 + lane * 8 + i], t[i]);
            }
            if (lane == 0) atomicAdd(&counts[g_cur], cnt);
            #pragma unroll
            for (int i = 0; i < 8; ++i) acc[i] = 0.f;
            cnt = 0;
            if (valid) {
                atomicAdd(&pooled[gl * 64 + c * 8 + 0], bf_lo(v.x));
                atomicAdd(&pooled[gl * 64 + c * 8 + 1], bf_hi(v.x));
                atomicAdd(&pooled[gl * 64 + c * 8 + 2], bf_lo(v.y));
                atomicAdd(&pooled[gl * 64 + c * 8 + 3], bf_hi(v.y));
                atomicAdd(&pooled[gl * 64 + c * 8 + 4], bf_lo(v.z));
                atomicAdd(&pooled[gl * 64 + c * 8 + 5], bf_hi(v.z));
                atomicAdd(&pooled[gl * 64 + c * 8 + 6], bf_lo(v.w));
                atomicAdd(&pooled[gl * 64 + c * 8 + 7], bf_hi(v.w));
                if (c == 0) atomicAdd(&counts[gl], 1);
            }
            g_cur = __shfl(gl, 56, 64);
        }
    }
    if (cnt > 0 && g_cur >= 0) {
        #pragma unroll
        for (int off = 8; off <= 32; off <<= 1) {
            #pragma unroll
            for (int i = 0; i < 8; ++i) acc[i] += __shfl_xor(acc[i], off, 64);
        }
        if (lane < 8) {
            #pragma unroll
            for (int i = 0; i < 8; ++i)
                atomicAdd(&pooled[g_cur * 64 + lane * 8 + i], acc[i]);
        }
        if (lane == 0) atomicAdd(&counts[g_cur], cnt);
    }
}

__global__ void head_kernel(const float* __restrict__ pooled, const int* __restrict__ counts,
                            const float* __restrict__ lin1_w, const float* __restrict__ lin1_b,
                            const float* __restrict__ lin2_w, const float* __restrict__ lin2_b,
                            float* __restrict__ out) {
    const int g = blockIdx.x;
    const int lane = threadIdx.x;
    const float c = fmaxf((float)counts[g], 1.0f);
    const float p = pooled[g * 64 + lane] / c;
    float d1 = wave_reduce_sum(p * lin1_w[lane]);
    float d2 = wave_reduce_sum(p * lin2_w[lane]);
    if (lane == 0) {
        out[g] = d1 + lin1_b[0];
        out[N_GRAPHS + g] = d2 + lin2_b[0];
    }
}

// ---------------------------------------------------------------------------
extern "C" void kernel_launch(void* const* d_in, const int* in_sizes, int n_in,
                              void* d_out, int out_size, void* d_ws, size_t ws_size,
                              hipStream_t stream) {
    const float* x       = (const float*)d_in[0];
    const int*   ei      = (const int*)d_in[1];
    const int*   batch   = (const int*)d_in[2];
    const float* W1_rel  = (const float*)d_in[3];
    const float* W1_root = (const float*)d_in[4];
    const float* b1      = (const float*)d_in[5];
    const float* W2_rel  = (const float*)d_in[6];
    const float* W2_root = (const float*)d_in[7];
    const float* b2      = (const float*)d_in[8];
    const float* W3_rel  = (const float*)d_in[9];
    const float* W3_root = (const float*)d_in[10];
    const float* b3      = (const float*)d_in[11];
    const float* lin1_w  = (const float*)d_in[12];
    const float* lin1_b  = (const float*)d_in[13];
    const float* lin2_w  = (const float*)d_in[14];
    const float* lin2_b  = (const float*)d_in[15];

    const int N = in_sizes[0] / 3;       // 50000  (< 65536, required for packing)
    const int E = in_sizes[1] / 2;       // 800000
    const int* src = ei;
    const int* dst = ei + E;
    const int NB = (N + 63) / 64;        // 782 coarse buckets

    char* ws = (char*)d_ws;
    size_t off = 0;
    auto alloc = [&](size_t bytes) -> void* {
        void* p = ws + off;
        off += (bytes + 255) & ~(size_t)255;
        return p;
    };
    int* rowptr   = (int*)alloc((size_t)(N + 1) * 4);
    int* csr_src  = (int*)alloc((size_t)E * 4);
    u32* ebuf     = (u32*)alloc((size_t)E * 4);
    u32* hist_g   = (u32*)alloc((size_t)NB * 4);
    u32* boff     = (u32*)alloc((size_t)(NB + 1) * 4);
    u32* cursor_g = (u32*)alloc((size_t)NB * 4);
    u16* bufA     = (u16*)alloc((size_t)N * HIDDEN * 2);
    u16* bufP     = (u16*)alloc((size_t)N * HIDDEN * 2);
    u16* bufB     = (u16*)alloc((size_t)N * HIDDEN * 2);
    u16* Bpk2     = (u16*)alloc(16 * 512 * 2);
    u16* Bpk3     = (u16*)alloc(16 * 512 * 2);
    float* pooled = (float*)alloc((size_t)N_GRAPHS * HIDDEN * 4);   // contiguous with counts
    int* counts   = (int*)alloc((size_t)N_GRAPHS * 4);

    hipMemsetAsync(hist_g, 0, (size_t)NB * 4, stream);
    hipMemsetAsync(pooled, 0, (size_t)N_GRAPHS * HIDDEN * 4 + 256, stream); // pooled+counts

    // ---- CSR build: 2-level counting sort ----
    const int K = 4096;                          // edges per partition block
    const int cb = (E + K - 1) / K;              // 196 blocks
    hist_kernel<<<256, 256, 0, stream>>>(dst, hist_g, E, NB);
    bscan_kernel<<<1, 1024, 0, stream>>>(hist_g, boff, cursor_g, rowptr, NB, N, E);
    partition_kernel<<<cb, 256, 0, stream>>>(src, dst, cursor_g, ebuf, E, NB, K);
    bucket_kernel<<<NB, 256, 0, stream>>>(boff, ebuf, rowptr, csr_src, N);

    prepack_kernel<<<2, 1024, 0, stream>>>(W2_rel, W2_root, W3_rel, W3_root, Bpk2, Bpk3);

    const int gb = (N + 3) / 4;          // gather: 1 node/wave, 4/block
    const int db = (N + 15) / 16;        // dense1: 4 nodes/wave, 16/block
    const int Ngrp = (N + 15) / 16;      // 16-node groups for MFMA dense
    const int mb = (Ngrp + 3) / 4;       // 4 waves/block

    dense1_kernel<<<db, 256, 0, stream>>>(x, W1_rel, W1_root, b1, bufP, bufB, N);
    gather_kernel<true ><<<gb, 256, 0, stream>>>(bufP, bufB, rowptr, csr_src, N);   // h1 in bufB
    dense_mfma_kernel<<<mb, 256, 0, stream>>>(bufB, Bpk2, b2, bufP, bufA, Ngrp);
    gather_kernel<true ><<<gb, 256, 0, stream>>>(bufP, bufA, rowptr, csr_src, N);   // h2 in bufA
    dense_mfma_kernel<<<mb, 256, 0, stream>>>(bufA, Bpk3, b3, bufP, bufB, Ngrp);
    gather_kernel<false><<<gb, 256, 0, stream>>>(bufP, bufB, rowptr, csr_src, N);   // h3 in bufB

    const int pool_waves = (N + 31) / 32;
    const int pool_blocks = (pool_waves + 3) / 4;
    pool_kernel<<<pool_blocks, 256, 0, stream>>>(bufB, batch, pooled, counts, N);
    head_kernel<<<N_GRAPHS, 64, 0, stream>>>(pooled, counts, lin1_w, lin1_b, lin2_w, lin2_b,
                                             (float*)d_out);
}